// Round 4
// baseline (555.862 us; speedup 1.0000x reference)
//
#include <hip/hip_runtime.h>

#define D   1024
#define S   4096
#define NB  16
#define NH  16
#define NSC 16

using bf16x8 = __attribute__((ext_vector_type(8))) short;
using f32x4  = __attribute__((ext_vector_type(4))) float;

__device__ __forceinline__ short f2bf(float f) {
    unsigned int u = __float_as_uint(f);
    u += 0x7fffu + ((u >> 16) & 1u);   // RNE
    return (short)(u >> 16);
}
__device__ __forceinline__ float bf2f(unsigned short u) {
    return __uint_as_float(((unsigned int)u) << 16);
}
__device__ __forceinline__ float elu1(float x) {
    return x > 0.f ? x + 1.f : __expf(x);   // elu(x)+1
}

// ---------------- y (f32) -> ybf (bf16) ----------------
__global__ __launch_bounds__(256) void ybf_kernel(const float* __restrict__ y,
        unsigned short* __restrict__ ybf)
{
    const size_t stride = (size_t)gridDim.x * 256 * 4;
    size_t idx = ((size_t)blockIdx.x * 256 + threadIdx.x) * 4;
    const size_t total = (size_t)NB * S * D;
    for (; idx < total; idx += stride) {
        const float4 v = *reinterpret_cast<const float4*>(y + idx);
        short4 p;
        p.x = f2bf(v.x); p.y = f2bf(v.y); p.z = f2bf(v.z); p.w = f2bf(v.w);
        *reinterpret_cast<short4*>(ybf + idx) = p;
    }
}

// ---------------- phi_q = elu(x @ Wq + bq) + 1 ----------------
__global__ __launch_bounds__(256) void phiq_kernel(const float* __restrict__ x,
        const float* __restrict__ Wq, const float* __restrict__ bq,
        float* __restrict__ phiq)
{
    const int b = blockIdx.y;
    const int o = blockIdx.x * 256 + threadIdx.x;
    __shared__ float xl[D];
    for (int i = threadIdx.x; i < D; i += 256) xl[i] = x[b * D + i];
    __syncthreads();
    float acc = bq[o];
    for (int j = 0; j < D; ++j) acc = fmaf(xl[j], Wq[(size_t)j * D + o], acc);
    phiq[b * D + o] = elu1(acc);
}

// ---------------- WkT[o][j] = bf16(Wk[j][o]) ----------------
__global__ __launch_bounds__(256) void wkt_kernel(const float* __restrict__ Wk,
        unsigned short* __restrict__ WkT)
{
    __shared__ float tile[32][33];
    const int tx = threadIdx.x & 31, ty = threadIdx.x >> 5;
    const int j0 = blockIdx.y * 32, o0 = blockIdx.x * 32;
#pragma unroll
    for (int r = 0; r < 4; ++r)
        tile[ty + r * 8][tx] = Wk[(size_t)(j0 + ty + r * 8) * D + o0 + tx];
    __syncthreads();
#pragma unroll
    for (int r = 0; r < 4; ++r) {
        const int o = o0 + ty + r * 8;
        WkT[(size_t)o * D + j0 + tx] = (unsigned short)f2bf(tile[tx][ty + r * 8]);
    }
}

// ---------------- fused K-projection + phi + phi_q reduction -> w[b,h,s] ----------------
// 256x256 tile, BK=64, 8 waves (2x4), double-buffered LDS (128 KB), pipelined:
//   prologue: STAGE(0)+STAGE(1); vmcnt(8); barrier
//   iter kt : read kk0 regs -> MFMA kk0 ; read kk1 regs ; lgkm(0)+barrier ;
//             STAGE(kt+2) into buf[kt&1] ; MFMA kk1 ; vmcnt(8) ; barrier
// Counted vmcnt keeps next tile's loads in flight across barriers (T3+T4); setprio (T5).
// LDS column-slot XOR swizzle via pre-swizzled global src (involution slot^=(row&7)).
__global__ __launch_bounds__(512, 1) void kgemm_kernel(
        const unsigned short* __restrict__ ybf, const unsigned short* __restrict__ WkT,
        const float* __restrict__ phiq, const float* __restrict__ bk,
        float* __restrict__ wbuf)
{
    const int bid = blockIdx.x;          // 0..1023
    const int wg  = (bid & 7) * 128 + (bid >> 3);   // XCD-chunked (1024 % 8 == 0)
    const int mt  = wg >> 2;             // 0..255 : A-strip (nt innermost for L2 reuse)
    const int nt  = wg & 3;
    const int b   = mt >> 4;
    const int s0  = (mt & 15) << 8;      // 256-row strip within batch b
    const int n0  = nt << 8;             // 256-col panel
    const int t   = threadIdx.x;
    const int wv  = t >> 6;              // 0..7
    const int l   = t & 63;
    const int wm  = wv >> 2, wn = wv & 3;
    const int l15 = l & 15, l16 = l >> 4;

    __shared__ short Al[2][256 * 64];    // 2 x 32 KB
    __shared__ short Bl[2][256 * 64];    // 2 x 32 KB

    f32x4 acc[8][4] = {};

    const unsigned short* yb = ybf + (size_t)(b * S + s0) * D;

#define STAGE(KT, BU) do {                                                         \
    const int _k0 = (KT) * 64;                                                     \
    _Pragma("unroll")                                                              \
    for (int _i = 0; _i < 4; ++_i) {                                               \
        const int _slot = _i * 512 + t;                                            \
        const int _row  = _slot >> 3;                                              \
        const int _ke   = ((_slot & 7) ^ (_row & 7)) << 3;                         \
        __builtin_amdgcn_global_load_lds(                                          \
            (const __attribute__((address_space(1))) unsigned int*)(yb + (size_t)_row * D + _k0 + _ke), \
            (__attribute__((address_space(3))) unsigned int*)(&Al[BU][(_i * 512 + wv * 64) * 8]), \
            16, 0, 0);                                                             \
    }                                                                              \
    _Pragma("unroll")                                                              \
    for (int _i = 0; _i < 4; ++_i) {                                               \
        const int _slot = _i * 512 + t;                                            \
        const int _row  = _slot >> 3;                                              \
        const int _ke   = ((_slot & 7) ^ (_row & 7)) << 3;                         \
        __builtin_amdgcn_global_load_lds(                                          \
            (const __attribute__((address_space(1))) unsigned int*)(WkT + (size_t)(n0 + _row) * D + _k0 + _ke), \
            (__attribute__((address_space(3))) unsigned int*)(&Bl[BU][(_i * 512 + wv * 64) * 8]), \
            16, 0, 0);                                                             \
    }                                                                              \
} while (0)

    // prologue: tiles 0 and 1 in flight
    STAGE(0, 0);
    STAGE(1, 1);
    asm volatile("s_waitcnt vmcnt(8)" ::: "memory");   // tile 0 landed (8 = tile 1's loads)
    __builtin_amdgcn_s_barrier();

#pragma unroll 2
    for (int kt = 0; kt < 16; ++kt) {
        const int bu = kt & 1;
        // ---- kk = 0 fragments ----
        bf16x8 a0[8], b0[4];
#pragma unroll
        for (int m = 0; m < 8; ++m) {
            const int row = wm * 128 + m * 16 + l15;
            a0[m] = *reinterpret_cast<const bf16x8*>(&Al[bu][row * 64 + ((l16 ^ (row & 7)) << 3)]);
        }
#pragma unroll
        for (int n = 0; n < 4; ++n) {
            const int row = wn * 64 + n * 16 + l15;
            b0[n] = *reinterpret_cast<const bf16x8*>(&Bl[bu][row * 64 + ((l16 ^ (row & 7)) << 3)]);
        }
        asm volatile("s_waitcnt lgkmcnt(0)" ::: "memory");
        __builtin_amdgcn_sched_barrier(0);
        __builtin_amdgcn_s_setprio(1);
#pragma unroll
        for (int m = 0; m < 8; ++m)
#pragma unroll
            for (int n = 0; n < 4; ++n)
                acc[m][n] = __builtin_amdgcn_mfma_f32_16x16x32_bf16(a0[m], b0[n], acc[m][n], 0, 0, 0);
        __builtin_amdgcn_s_setprio(0);
        // ---- kk = 1 fragments ----
        bf16x8 a1[8], b1[4];
#pragma unroll
        for (int m = 0; m < 8; ++m) {
            const int row = wm * 128 + m * 16 + l15;
            a1[m] = *reinterpret_cast<const bf16x8*>(&Al[bu][row * 64 + (((4 + l16) ^ (row & 7)) << 3)]);
        }
#pragma unroll
        for (int n = 0; n < 4; ++n) {
            const int row = wn * 64 + n * 16 + l15;
            b1[n] = *reinterpret_cast<const bf16x8*>(&Bl[bu][row * 64 + (((4 + l16) ^ (row & 7)) << 3)]);
        }
        asm volatile("s_waitcnt lgkmcnt(0)" ::: "memory");
        __builtin_amdgcn_sched_barrier(0);
        __builtin_amdgcn_s_barrier();                  // all waves done reading buf[bu]
        if (kt + 2 < 16) STAGE(kt + 2, bu);            // safe to overwrite now
        __builtin_amdgcn_s_setprio(1);
#pragma unroll
        for (int m = 0; m < 8; ++m)
#pragma unroll
            for (int n = 0; n < 4; ++n)
                acc[m][n] = __builtin_amdgcn_mfma_f32_16x16x32_bf16(a1[m], b1[n], acc[m][n], 0, 0, 0);
        __builtin_amdgcn_s_setprio(0);
        if (kt < 14) { asm volatile("s_waitcnt vmcnt(8)" ::: "memory"); }
        else         { asm volatile("s_waitcnt vmcnt(0)" ::: "memory"); }
        __builtin_amdgcn_s_barrier();                  // tile kt+1 fully in LDS
    }
#undef STAGE

    // epilogue: wave wn covers head h = nt*4 + wn (cols n0 + wn*64 .. +63)
    const int h = (n0 >> 6) + wn;
    float pq[4], bkv[4];
#pragma unroll
    for (int n = 0; n < 4; ++n) {
        const int col = n0 + wn * 64 + n * 16 + l15;
        pq[n]  = phiq[b * D + col];
        bkv[n] = bk[col];
    }
#pragma unroll
    for (int m = 0; m < 8; ++m) {
#pragma unroll
        for (int j = 0; j < 4; ++j) {
            float rs = 0.f;
#pragma unroll
            for (int n = 0; n < 4; ++n)
                rs += elu1(acc[m][n][j] + bkv[n]) * pq[n];
            rs += __shfl_xor(rs, 1);
            rs += __shfl_xor(rs, 2);
            rs += __shfl_xor(rs, 4);
            rs += __shfl_xor(rs, 8);
            if (l15 == 0) {
                const int row = s0 + wm * 128 + m * 16 + l16 * 4 + j;
                wbuf[(size_t)(b * NH + h) * S + row] = rs;
            }
        }
    }
}

// ---------------- t_part[sc][b][h][j] = sum_{s in chunk} w[b,h,s] * ybf[b,s,j] ----------------
__global__ __launch_bounds__(256) void tpart_kernel(
        const unsigned short* __restrict__ ybf, const float* __restrict__ wbuf,
        float* __restrict__ tpart)
{
    const int sc = blockIdx.x;   // 0..15 (256 s each)
    const int b  = blockIdx.y;
    const int t  = threadIdx.x;
    const int s0 = sc * 256;
    __shared__ float wl[16 * 256];
#pragma unroll
    for (int r = 0; r < 16; ++r) {
        const int lin = r * 256 + t;
        wl[lin] = wbuf[(size_t)(b * NH + (lin >> 8)) * S + s0 + (lin & 255)];
    }
    __syncthreads();
    float acc[16][4] = {};
    const unsigned short* yb = ybf + (size_t)(b * S + s0) * D + t * 4;
    for (int si = 0; si < 256; ++si) {
        const short4 v4 = *reinterpret_cast<const short4*>(yb + (size_t)si * D);
        const float vx = bf2f((unsigned short)v4.x);
        const float vy = bf2f((unsigned short)v4.y);
        const float vz = bf2f((unsigned short)v4.z);
        const float vw = bf2f((unsigned short)v4.w);
#pragma unroll
        for (int hh = 0; hh < 16; ++hh) {
            const float wv = wl[hh * 256 + si];
            acc[hh][0] = fmaf(wv, vx, acc[hh][0]);
            acc[hh][1] = fmaf(wv, vy, acc[hh][1]);
            acc[hh][2] = fmaf(wv, vz, acc[hh][2]);
            acc[hh][3] = fmaf(wv, vw, acc[hh][3]);
        }
    }
    float* tp = tpart + ((size_t)(sc * NB + b) * NH) * D + t * 4;
#pragma unroll
    for (int hh = 0; hh < 16; ++hh) {
        float4 o;
        o.x = acc[hh][0]; o.y = acc[hh][1]; o.z = acc[hh][2]; o.w = acc[hh][3];
        *reinterpret_cast<float4*>(tp + hh * D) = o;
    }
}

__global__ __launch_bounds__(256) void tred_kernel(const float* __restrict__ tpart,
        float* __restrict__ tbuf)
{
    const int idx = blockIdx.x * 256 + threadIdx.x;
    float s = 0.f;
#pragma unroll
    for (int sc = 0; sc < NSC; ++sc) s += tpart[(size_t)sc * (NB * NH * D) + idx];
    tbuf[idx] = s;
}

// ---------------- ctx[b, h*64+v] ----------------
__global__ __launch_bounds__(256) void ctx_kernel(
        const float* __restrict__ wbuf, const float* __restrict__ tbuf,
        const float* __restrict__ Wv, const float* __restrict__ bv,
        float* __restrict__ ctx)
{
    const int b = blockIdx.x >> 4, h = blockIdx.x & 15;
    const int t = threadIdx.x;
    const int v = t & 63, jq = t >> 6;
    __shared__ float rnum[256];
    __shared__ float rden[4];
    const float* wr_ = wbuf + (size_t)(b * NH + h) * S;
    float dp = 0.f;
    for (int i = t; i < S; i += 256) dp += wr_[i];
#pragma unroll
    for (int off = 1; off < 64; off <<= 1) dp += __shfl_xor(dp, off);
    if ((t & 63) == 0) rden[t >> 6] = dp;
    const float* tr = tbuf + (size_t)(b * NH + h) * D;
    float np = 0.f;
    for (int j = jq * 256; j < jq * 256 + 256; ++j)
        np = fmaf(tr[j], Wv[(size_t)j * D + h * 64 + v], np);
    rnum[t] = np;
    __syncthreads();
    if (t < 64) {
        const float denom = rden[0] + rden[1] + rden[2] + rden[3];
        float num = rnum[v] + rnum[64 + v] + rnum[128 + v] + rnum[192 + v];
        num += denom * bv[h * 64 + v];
        ctx[(size_t)b * D + h * 64 + v] = num / (denom + 1e-6f);
    }
}

// ---------------- out = ctx @ Wo + bo ----------------
__global__ __launch_bounds__(256) void out_kernel(
        const float* __restrict__ ctx, const float* __restrict__ Wo,
        const float* __restrict__ bo, float* __restrict__ out)
{
    const int b = blockIdx.y;
    const int o = blockIdx.x * 256 + threadIdx.x;
    __shared__ float cl[D];
    for (int i = threadIdx.x; i < D; i += 256) cl[i] = ctx[(size_t)b * D + i];
    __syncthreads();
    float acc = bo[o];
    for (int j = 0; j < D; ++j) acc = fmaf(cl[j], Wo[(size_t)j * D + o], acc);
    out[(size_t)b * D + o] = acc;
}

extern "C" void kernel_launch(void* const* d_in, const int* in_sizes, int n_in,
                              void* d_out, int out_size, void* d_ws, size_t ws_size,
                              hipStream_t stream) {
    const float* y  = (const float*)d_in[0];
    const float* x  = (const float*)d_in[1];
    const float* Wq = (const float*)d_in[2];
    const float* bq = (const float*)d_in[3];
    const float* Wk = (const float*)d_in[4];
    const float* bk = (const float*)d_in[5];
    const float* Wv = (const float*)d_in[6];
    const float* bv = (const float*)d_in[7];
    const float* Wo = (const float*)d_in[8];
    const float* bo = (const float*)d_in[9];
    float* out = (float*)d_out;

    char* ws = (char*)d_ws;
    size_t off = 0;
    unsigned short* ybf  = (unsigned short*)(ws + off); off += (size_t)NB * S * D * 2;        // 128 MB
    unsigned short* WkT  = (unsigned short*)(ws + off); off += (size_t)D * D * 2;             // 2 MB
    float*          phiq = (float*)(ws + off);          off += (size_t)NB * D * 4;            // 64 KB
    float*          wbuf = (float*)(ws + off);          off += (size_t)NB * NH * S * 4;       // 4 MB
    float*          tpart= (float*)(ws + off);          off += (size_t)NSC * NB * NH * D * 4; // 16 MB
    float*          tbuf = (float*)(ws + off);          off += (size_t)NB * NH * D * 4;       // 1 MB
    float*          ctx  = (float*)(ws + off);          off += (size_t)NB * D * 4;            // 64 KB

    ybf_kernel <<<2048, 256, 0, stream>>>(y, ybf);
    phiq_kernel<<<dim3(4, NB), 256, 0, stream>>>(x, Wq, bq, phiq);
    wkt_kernel <<<dim3(32, 32), 256, 0, stream>>>(Wk, WkT);
    kgemm_kernel<<<1024, 512, 0, stream>>>(ybf, WkT, phiq, bk, wbuf);
    tpart_kernel<<<dim3(NSC, NB), 256, 0, stream>>>(ybf, wbuf, tpart);
    tred_kernel <<<1024, 256, 0, stream>>>(tpart, tbuf);
    ctx_kernel  <<<256, 256, 0, stream>>>(wbuf, tbuf, Wv, bv, ctx);
    out_kernel  <<<dim3(4, NB), 256, 0, stream>>>(ctx, Wo, bo, out);
}

// Round 5
// 410.421 us; speedup vs baseline: 1.3544x; 1.3544x over previous
//
#include <hip/hip_runtime.h>

#define D   1024
#define S   4096
#define NB  16
#define NH  16
#define NSC 16

using bf16x8 = __attribute__((ext_vector_type(8))) short;
using f32x4  = __attribute__((ext_vector_type(4))) float;

__device__ __forceinline__ short f2bf(float f) {
    unsigned int u = __float_as_uint(f);
    u += 0x7fffu + ((u >> 16) & 1u);   // RNE
    return (short)(u >> 16);
}
__device__ __forceinline__ float bf2f(unsigned short u) {
    return __uint_as_float(((unsigned int)u) << 16);
}
__device__ __forceinline__ float elu1(float x) {
    return x > 0.f ? x + 1.f : __expf(x);   // elu(x)+1
}

// ---------------- y (f32) -> ybf (bf16) ----------------
__global__ __launch_bounds__(256) void ybf_kernel(const float* __restrict__ y,
        unsigned short* __restrict__ ybf)
{
    const size_t stride = (size_t)gridDim.x * 256 * 4;
    size_t idx = ((size_t)blockIdx.x * 256 + threadIdx.x) * 4;
    const size_t total = (size_t)NB * S * D;
    for (; idx < total; idx += stride) {
        const float4 v = *reinterpret_cast<const float4*>(y + idx);
        short4 p;
        p.x = f2bf(v.x); p.y = f2bf(v.y); p.z = f2bf(v.z); p.w = f2bf(v.w);
        *reinterpret_cast<short4*>(ybf + idx) = p;
    }
}

// ---------------- phi_q = elu(x @ Wq + bq) + 1 ----------------
__global__ __launch_bounds__(256) void phiq_kernel(const float* __restrict__ x,
        const float* __restrict__ Wq, const float* __restrict__ bq,
        float* __restrict__ phiq)
{
    const int b = blockIdx.y;
    const int o = blockIdx.x * 256 + threadIdx.x;
    __shared__ float xl[D];
    for (int i = threadIdx.x; i < D; i += 256) xl[i] = x[b * D + i];
    __syncthreads();
    float acc = bq[o];
    for (int j = 0; j < D; ++j) acc = fmaf(xl[j], Wq[(size_t)j * D + o], acc);
    phiq[b * D + o] = elu1(acc);
}

// ---------------- WkT[o][j] = bf16(Wk[j][o]) ----------------
__global__ __launch_bounds__(256) void wkt_kernel(const float* __restrict__ Wk,
        unsigned short* __restrict__ WkT)
{
    __shared__ float tile[32][33];
    const int tx = threadIdx.x & 31, ty = threadIdx.x >> 5;
    const int j0 = blockIdx.y * 32, o0 = blockIdx.x * 32;
#pragma unroll
    for (int r = 0; r < 4; ++r)
        tile[ty + r * 8][tx] = Wk[(size_t)(j0 + ty + r * 8) * D + o0 + tx];
    __syncthreads();
#pragma unroll
    for (int r = 0; r < 4; ++r) {
        const int o = o0 + ty + r * 8;
        WkT[(size_t)o * D + j0 + tx] = (unsigned short)f2bf(tile[tx][ty + r * 8]);
    }
}

// ---------------- fused K-projection + phi + phi_q reduction -> w[b,h,s] ----------------
// 256x256 tile, BK=64, 8 waves (2x4), double-buffered LDS (128 KB).
//   prologue: STAGE(0,buf0)+STAGE(1,buf1); vmcnt(8); barrier
//   iter kt : compute tile kt from buf[kt&1] (compiler schedules ds_read<->MFMA);
//             lgkm(0); barrier (all waves done reading buf);
//             STAGE(kt+2) into buf[kt&1]; vmcnt(8) [kt+1 landed, kt+2 in flight]; barrier
// No sched_barrier walls (R4 lesson: they forced 96 VGPRs of fragments live -> spill).
// amdgpu_waves_per_eu(2,2): LDS already caps at 1 block/CU (2 waves/SIMD), so let the
// allocator use the full 256-VGPR budget instead of spilling at a 128 target.
__global__ __launch_bounds__(512) __attribute__((amdgpu_waves_per_eu(2, 2)))
void kgemm_kernel(
        const unsigned short* __restrict__ ybf, const unsigned short* __restrict__ WkT,
        const float* __restrict__ phiq, const float* __restrict__ bk,
        float* __restrict__ wbuf)
{
    const int bid = blockIdx.x;          // 0..1023
    const int wg  = (bid & 7) * 128 + (bid >> 3);   // XCD-chunked (1024 % 8 == 0)
    const int mt  = wg >> 2;             // 0..255 : A-strip (nt innermost for L2 reuse)
    const int nt  = wg & 3;
    const int b   = mt >> 4;
    const int s0  = (mt & 15) << 8;      // 256-row strip within batch b
    const int n0  = nt << 8;             // 256-col panel
    const int t   = threadIdx.x;
    const int wv  = t >> 6;              // 0..7
    const int l   = t & 63;
    const int wm  = wv >> 2, wn = wv & 3;
    const int l15 = l & 15, l16 = l >> 4;

    __shared__ short Al[2][256 * 64];    // 2 x 32 KB
    __shared__ short Bl[2][256 * 64];    // 2 x 32 KB

    f32x4 acc[8][4] = {};

    const unsigned short* yb = ybf + (size_t)(b * S + s0) * D;

#define STAGE(KT, BU) do {                                                         \
    const int _k0 = (KT) * 64;                                                     \
    _Pragma("unroll")                                                              \
    for (int _i = 0; _i < 4; ++_i) {                                               \
        const int _slot = _i * 512 + t;                                            \
        const int _row  = _slot >> 3;                                              \
        const int _ke   = ((_slot & 7) ^ (_row & 7)) << 3;                         \
        __builtin_amdgcn_global_load_lds(                                          \
            (const __attribute__((address_space(1))) unsigned int*)(yb + (size_t)_row * D + _k0 + _ke), \
            (__attribute__((address_space(3))) unsigned int*)(&Al[BU][(_i * 512 + wv * 64) * 8]), \
            16, 0, 0);                                                             \
    }                                                                              \
    _Pragma("unroll")                                                              \
    for (int _i = 0; _i < 4; ++_i) {                                               \
        const int _slot = _i * 512 + t;                                            \
        const int _row  = _slot >> 3;                                              \
        const int _ke   = ((_slot & 7) ^ (_row & 7)) << 3;                         \
        __builtin_amdgcn_global_load_lds(                                          \
            (const __attribute__((address_space(1))) unsigned int*)(WkT + (size_t)(n0 + _row) * D + _k0 + _ke), \
            (__attribute__((address_space(3))) unsigned int*)(&Bl[BU][(_i * 512 + wv * 64) * 8]), \
            16, 0, 0);                                                             \
    }                                                                              \
} while (0)

    // prologue: tiles 0 and 1 in flight
    STAGE(0, 0);
    STAGE(1, 1);
    asm volatile("s_waitcnt vmcnt(8)" ::: "memory");   // tile 0 landed (8 = tile 1's loads)
    __builtin_amdgcn_s_barrier();

    for (int kt = 0; kt < 16; ++kt) {
        const int bu = kt & 1;
        __builtin_amdgcn_s_setprio(1);
#pragma unroll
        for (int kk = 0; kk < 2; ++kk) {
            bf16x8 af[8], bfr[4];
            const int ks = (kk << 2) + l16;   // column-slot 0..7
#pragma unroll
            for (int m = 0; m < 8; ++m) {
                const int row = wm * 128 + m * 16 + l15;
                af[m] = *reinterpret_cast<const bf16x8*>(&Al[bu][row * 64 + ((ks ^ (row & 7)) << 3)]);
            }
#pragma unroll
            for (int n = 0; n < 4; ++n) {
                const int row = wn * 64 + n * 16 + l15;
                bfr[n] = *reinterpret_cast<const bf16x8*>(&Bl[bu][row * 64 + ((ks ^ (row & 7)) << 3)]);
            }
#pragma unroll
            for (int m = 0; m < 8; ++m)
#pragma unroll
                for (int n = 0; n < 4; ++n)
                    acc[m][n] = __builtin_amdgcn_mfma_f32_16x16x32_bf16(af[m], bfr[n], acc[m][n], 0, 0, 0);
        }
        __builtin_amdgcn_s_setprio(0);
        asm volatile("s_waitcnt lgkmcnt(0)" ::: "memory");  // my ds_reads of buf[bu] drained
        __builtin_amdgcn_s_barrier();                       // all waves done reading buf[bu]
        if (kt + 2 < 16) STAGE(kt + 2, bu);                 // safe to overwrite now
        if (kt < 14) { asm volatile("s_waitcnt vmcnt(8)" ::: "memory"); }
        else         { asm volatile("s_waitcnt vmcnt(0)" ::: "memory"); }
        __builtin_amdgcn_s_barrier();                       // tile kt+1 fully in LDS
    }
#undef STAGE

    // epilogue: wave wn covers head h = nt*4 + wn (cols n0 + wn*64 .. +63)
    const int h = (n0 >> 6) + wn;
    float pq[4], bkv[4];
#pragma unroll
    for (int n = 0; n < 4; ++n) {
        const int col = n0 + wn * 64 + n * 16 + l15;
        pq[n]  = phiq[b * D + col];
        bkv[n] = bk[col];
    }
#pragma unroll
    for (int m = 0; m < 8; ++m) {
#pragma unroll
        for (int j = 0; j < 4; ++j) {
            float rs = 0.f;
#pragma unroll
            for (int n = 0; n < 4; ++n)
                rs += elu1(acc[m][n][j] + bkv[n]) * pq[n];
            rs += __shfl_xor(rs, 1);
            rs += __shfl_xor(rs, 2);
            rs += __shfl_xor(rs, 4);
            rs += __shfl_xor(rs, 8);
            if (l15 == 0) {
                const int row = s0 + wm * 128 + m * 16 + l16 * 4 + j;
                wbuf[(size_t)(b * NH + h) * S + row] = rs;
            }
        }
    }
}

// ---------------- t_part[sc][b][h][j] = sum_{s in chunk} w[b,h,s] * ybf[b,s,j] ----------------
__global__ __launch_bounds__(256) void tpart_kernel(
        const unsigned short* __restrict__ ybf, const float* __restrict__ wbuf,
        float* __restrict__ tpart)
{
    const int sc = blockIdx.x;   // 0..15 (256 s each)
    const int b  = blockIdx.y;
    const int t  = threadIdx.x;
    const int s0 = sc * 256;
    __shared__ float wl[16 * 256];
#pragma unroll
    for (int r = 0; r < 16; ++r) {
        const int lin = r * 256 + t;
        wl[lin] = wbuf[(size_t)(b * NH + (lin >> 8)) * S + s0 + (lin & 255)];
    }
    __syncthreads();
    float acc[16][4] = {};
    const unsigned short* yb = ybf + (size_t)(b * S + s0) * D + t * 4;
    for (int si = 0; si < 256; ++si) {
        const short4 v4 = *reinterpret_cast<const short4*>(yb + (size_t)si * D);
        const float vx = bf2f((unsigned short)v4.x);
        const float vy = bf2f((unsigned short)v4.y);
        const float vz = bf2f((unsigned short)v4.z);
        const float vw = bf2f((unsigned short)v4.w);
#pragma unroll
        for (int hh = 0; hh < 16; ++hh) {
            const float wv = wl[hh * 256 + si];
            acc[hh][0] = fmaf(wv, vx, acc[hh][0]);
            acc[hh][1] = fmaf(wv, vy, acc[hh][1]);
            acc[hh][2] = fmaf(wv, vz, acc[hh][2]);
            acc[hh][3] = fmaf(wv, vw, acc[hh][3]);
        }
    }
    float* tp = tpart + ((size_t)(sc * NB + b) * NH) * D + t * 4;
#pragma unroll
    for (int hh = 0; hh < 16; ++hh) {
        float4 o;
        o.x = acc[hh][0]; o.y = acc[hh][1]; o.z = acc[hh][2]; o.w = acc[hh][3];
        *reinterpret_cast<float4*>(tp + hh * D) = o;
    }
}

__global__ __launch_bounds__(256) void tred_kernel(const float* __restrict__ tpart,
        float* __restrict__ tbuf)
{
    const int idx = blockIdx.x * 256 + threadIdx.x;
    float s = 0.f;
#pragma unroll
    for (int sc = 0; sc < NSC; ++sc) s += tpart[(size_t)sc * (NB * NH * D) + idx];
    tbuf[idx] = s;
}

// ---------------- ctx[b, h*64+v] ----------------
__global__ __launch_bounds__(256) void ctx_kernel(
        const float* __restrict__ wbuf, const float* __restrict__ tbuf,
        const float* __restrict__ Wv, const float* __restrict__ bv,
        float* __restrict__ ctx)
{
    const int b = blockIdx.x >> 4, h = blockIdx.x & 15;
    const int t = threadIdx.x;
    const int v = t & 63, jq = t >> 6;
    __shared__ float rnum[256];
    __shared__ float rden[4];
    const float* wr_ = wbuf + (size_t)(b * NH + h) * S;
    float dp = 0.f;
    for (int i = t; i < S; i += 256) dp += wr_[i];
#pragma unroll
    for (int off = 1; off < 64; off <<= 1) dp += __shfl_xor(dp, off);
    if ((t & 63) == 0) rden[t >> 6] = dp;
    const float* tr = tbuf + (size_t)(b * NH + h) * D;
    float np = 0.f;
    for (int j = jq * 256; j < jq * 256 + 256; ++j)
        np = fmaf(tr[j], Wv[(size_t)j * D + h * 64 + v], np);
    rnum[t] = np;
    __syncthreads();
    if (t < 64) {
        const float denom = rden[0] + rden[1] + rden[2] + rden[3];
        float num = rnum[v] + rnum[64 + v] + rnum[128 + v] + rnum[192 + v];
        num += denom * bv[h * 64 + v];
        ctx[(size_t)b * D + h * 64 + v] = num / (denom + 1e-6f);
    }
}

// ---------------- out = ctx @ Wo + bo ----------------
__global__ __launch_bounds__(256) void out_kernel(
        const float* __restrict__ ctx, const float* __restrict__ Wo,
        const float* __restrict__ bo, float* __restrict__ out)
{
    const int b = blockIdx.y;
    const int o = blockIdx.x * 256 + threadIdx.x;
    __shared__ float cl[D];
    for (int i = threadIdx.x; i < D; i += 256) cl[i] = ctx[(size_t)b * D + i];
    __syncthreads();
    float acc = bo[o];
    for (int j = 0; j < D; ++j) acc = fmaf(cl[j], Wo[(size_t)j * D + o], acc);
    out[(size_t)b * D + o] = acc;
}

extern "C" void kernel_launch(void* const* d_in, const int* in_sizes, int n_in,
                              void* d_out, int out_size, void* d_ws, size_t ws_size,
                              hipStream_t stream) {
    const float* y  = (const float*)d_in[0];
    const float* x  = (const float*)d_in[1];
    const float* Wq = (const float*)d_in[2];
    const float* bq = (const float*)d_in[3];
    const float* Wk = (const float*)d_in[4];
    const float* bk = (const float*)d_in[5];
    const float* Wv = (const float*)d_in[6];
    const float* bv = (const float*)d_in[7];
    const float* Wo = (const float*)d_in[8];
    const float* bo = (const float*)d_in[9];
    float* out = (float*)d_out;

    char* ws = (char*)d_ws;
    size_t off = 0;
    unsigned short* ybf  = (unsigned short*)(ws + off); off += (size_t)NB * S * D * 2;        // 128 MB
    unsigned short* WkT  = (unsigned short*)(ws + off); off += (size_t)D * D * 2;             // 2 MB
    float*          phiq = (float*)(ws + off);          off += (size_t)NB * D * 4;            // 64 KB
    float*          wbuf = (float*)(ws + off);          off += (size_t)NB * NH * S * 4;       // 4 MB
    float*          tpart= (float*)(ws + off);          off += (size_t)NSC * NB * NH * D * 4; // 16 MB
    float*          tbuf = (float*)(ws + off);          off += (size_t)NB * NH * D * 4;       // 1 MB
    float*          ctx  = (float*)(ws + off);          off += (size_t)NB * D * 4;            // 64 KB

    ybf_kernel <<<2048, 256, 0, stream>>>(y, ybf);
    phiq_kernel<<<dim3(4, NB), 256, 0, stream>>>(x, Wq, bq, phiq);
    wkt_kernel <<<dim3(32, 32), 256, 0, stream>>>(Wk, WkT);
    kgemm_kernel<<<1024, 512, 0, stream>>>(ybf, WkT, phiq, bk, wbuf);
    tpart_kernel<<<dim3(NSC, NB), 256, 0, stream>>>(ybf, wbuf, tpart);
    tred_kernel <<<1024, 256, 0, stream>>>(tpart, tbuf);
    ctx_kernel  <<<256, 256, 0, stream>>>(wbuf, tbuf, Wv, bv, ctx);
    out_kernel  <<<dim3(4, NB), 256, 0, stream>>>(ctx, Wo, bo, out);
}